// Round 3
// baseline (149.300 us; speedup 1.0000x reference)
//
#include <hip/hip_runtime.h>
#include <math.h>

// Problem constants (B=2, C=128, G=16, Cg=8, K=3, H=W=192)
#define BB 2
#define CC 128
#define GG 16
#define CG 8
#define HH 192
#define WW 192
#define HM 190
#define WM 190
#define HWSZ (HH * WW)        // 36864
#define NTRIPLE (BB * GG * 9) // 288
#define SPLIT 6               // row slices for phase1 parallelism
#define ROWS_PER_SLICE 32     // 6*32 >= 190

typedef float float4a __attribute__((ext_vector_type(4), aligned(4)));
typedef float float4v __attribute__((ext_vector_type(4)));

// Module-owned scratch (d_ws size unverified; writing it corrupted the
// harness pristine input copy in a previous session). Each array is fully
// rewritten every call before being read; kernel boundaries provide
// agent-scope coherence (no fences anywhere -- the R1 lesson: a
// __threadfence per block cost ~70 us in L2 writebacks).
__device__ float g_part[NTRIPLE * SPLIT * 36]; // per-slice partial sums
__device__ int g_rel[BB * GG * 72];            // neighbor rel offset table
__device__ float g_scl[BB * GG * 72];          // c_max/8 table

// Is window row (ci,ki) referenced by any of triple J's 8 vectors?
constexpr bool row_used(int J, int ci, int ki) {
  for (int d = 0; d < 8; ++d) {
    const int f = 8 * J + d;
    if ((f / 9 - (8 * J) / 9) == ci && (f % 9) / 3 == ki) return true;
  }
  return false;
}

// -------- Phase 1 gram partials: aligned-window, high-ILP ----------------
// v3: 256-thread blocks (was 128) -> 27 waves/CU resident (was 13.5).
// Phase1 is latency-bound (VALU floor ~5us vs ~40us measured, VALUBusy
// ~13%), so doubling resident waves is the direct lever. VGPR stays ~72
// -> up to 7 waves/SIMD allowed; no spill risk (no manual unroll added
// precisely to keep VGPR low).
template <int J>
__device__ __forceinline__ void gram_slice(const float* __restrict__ pA,
                                           const float* __restrict__ pB,
                                           int y0, int rows, int tid,
                                           float acc[36]) {
  constexpr int CA = (8 * J) / 9;
  constexpr int CB = (8 * J + 7) / 9;
  constexpr int NCH = (CB > CA) ? 2 : 1;

  // ---- main: 4-px groups, x0 in {0,4,...,184}, px x in [0,188) ----
  const int ngrp = rows * 47;
  for (int q = tid; q < ngrp; q += 256) {
    const int y = y0 + q / 47;
    const int x0 = (q % 47) * 4;
    const int ro = y * WW + x0; // multiple of 4 -> 16B-aligned address

    float w[NCH][3][8];
#pragma unroll
    for (int ci = 0; ci < NCH; ++ci) {
      const float* pc = ci ? pB : pA;
#pragma unroll
      for (int ki = 0; ki < 3; ++ki) {
        if (row_used(J, ci, ki)) {
          const float4v a = *(const float4v*)(pc + ro + ki * WW);
          const float4v bq = *(const float4v*)(pc + ro + ki * WW + 4);
          w[ci][ki][0] = a.x; w[ci][ki][1] = a.y;
          w[ci][ki][2] = a.z; w[ci][ki][3] = a.w;
          w[ci][ki][4] = bq.x; w[ci][ki][5] = bq.y;
          w[ci][ki][6] = bq.z; w[ci][ki][7] = bq.w;
        }
      }
    }
    // squares
#pragma unroll
    for (int d = 0; d < 8; ++d) {
      const int f = 8 * J + d;
      const int ci = f / 9 - CA;
      const int k = f % 9;
      const int ki = k / 3, kj = k % 3;
      float s = 0.0f;
#pragma unroll
      for (int e = 0; e < 4; ++e) s += w[ci][ki][kj + e] * w[ci][ki][kj + e];
      acc[d] += s;
    }
    // cross products (same (c,d) order the reduction expects)
    int p = 8;
#pragma unroll
    for (int c = 0; c < 8; ++c) {
      const int f1 = 8 * J + c;
      const int ci1 = f1 / 9 - CA;
      const int k1 = f1 % 9;
      const int ki1 = k1 / 3, kj1 = k1 % 3;
#pragma unroll
      for (int d = c + 1; d < 8; ++d) {
        const int f2 = 8 * J + d;
        const int ci2 = f2 / 9 - CA;
        const int k2 = f2 % 9;
        const int ki2 = k2 / 3, kj2 = k2 % 3;
        float s = 0.0f;
#pragma unroll
        for (int e = 0; e < 4; ++e)
          s += w[ci1][ki1][kj1 + e] * w[ci2][ki2][kj2 + e];
        acc[p++] += s;
      }
    }
  }

  // ---- cleanup: px x in {188,189}, scalar ----
  const int ncl = rows * 2;
  for (int t = tid; t < ncl; t += 256) {
    const int y = y0 + t / 2;
    const int x = 188 + (t & 1);
    float v[8];
#pragma unroll
    for (int d = 0; d < 8; ++d) {
      const int f = 8 * J + d;
      const int ci = f / 9 - CA;
      const int k = f % 9;
      const int ki = k / 3, kj = k % 3;
      v[d] = (ci ? pB : pA)[(y + ki) * WW + x + kj];
    }
#pragma unroll
    for (int d = 0; d < 8; ++d) acc[d] += v[d] * v[d];
    int p = 8;
#pragma unroll
    for (int c = 0; c < 8; ++c)
#pragma unroll
      for (int d = c + 1; d < 8; ++d) acc[p++] += v[c] * v[d];
  }
}

// -------- Phase 1: gram partials only (no fences, no atomics) ------------
__global__ __launch_bounds__(256, 4) void phase1_kernel(
    const float* __restrict__ feat) {
  const int B = blockIdx.x;      // 0..1727
  const int xcd = B & 7;         // XCD-locality swizzle (kept: halved FETCH)
  const int slot = B >> 3;       // 0..215
  const int unit = xcd * 4 + slot / 54; // (b,g) composite, 0..31
  const int r = slot % 54;
  const int j = r / 6;
  const int sl = r % 6;
  const int b = unit >> 4;
  const int g = unit & 15;

  const int cA = (8 * j) / 9;
  const int cB = (8 * j + 7) / 9;
  const float* pA = feat + (size_t)(b * CC + g * CG + cA) * HWSZ;
  const float* pB = feat + (size_t)(b * CC + g * CG + cB) * HWSZ;

  const int y0 = sl * ROWS_PER_SLICE;
  const int y1 = (y0 + ROWS_PER_SLICE < HM) ? y0 + ROWS_PER_SLICE : HM;
  const int rows = y1 - y0;
  const int tid = (int)threadIdx.x;

  float acc[36];
#pragma unroll
  for (int i = 0; i < 36; ++i) acc[i] = 0.0f;

  switch (j) {
    case 0: gram_slice<0>(pA, pB, y0, rows, tid, acc); break;
    case 1: gram_slice<1>(pA, pB, y0, rows, tid, acc); break;
    case 2: gram_slice<2>(pA, pB, y0, rows, tid, acc); break;
    case 3: gram_slice<3>(pA, pB, y0, rows, tid, acc); break;
    case 4: gram_slice<4>(pA, pB, y0, rows, tid, acc); break;
    case 5: gram_slice<5>(pA, pB, y0, rows, tid, acc); break;
    case 6: gram_slice<6>(pA, pB, y0, rows, tid, acc); break;
    case 7: gram_slice<7>(pA, pB, y0, rows, tid, acc); break;
    default: gram_slice<8>(pA, pB, y0, rows, tid, acc); break;
  }

  // Wave shuffle reduce (64 lanes) then LDS across 4 waves.
  __shared__ float red[36 * 4];
  const int lane = tid & 63;
  const int wave = tid >> 6;
#pragma unroll
  for (int i = 0; i < 36; ++i) {
    float v = acc[i];
    for (int o = 32; o > 0; o >>= 1) v += __shfl_down(v, o, 64);
    if (lane == 0) red[i * 4 + wave] = v;
  }
  __syncthreads();
  if (tid < 36) {
    const int tri = unit * 9 + j;
    g_part[(tri * SPLIT + sl) * 36 + tid] =
        ((red[tid * 4] + red[tid * 4 + 1]) + red[tid * 4 + 2]) +
        red[tid * 4 + 3];
  }
}

// -------- Phase 1b: reduce slices, 8x8 argmin, emit phase2 tables ---------
// Tiny kernel (5 blocks); the launch boundary is what makes g_part coherent
// for free. Its ~3us cost beats the per-block argmin redundancy it replaces
// (R2 post-mortem: inline-argmin prologue in 4608 phase2 blocks cost ~10us).
__global__ __launch_bounds__(64) void phase1b_kernel() {
  const int tri = blockIdx.x * 64 + (int)threadIdx.x;
  if (tri >= NTRIPLE) return;
  const int b = tri / (GG * 9);
  const int rem = tri % (GG * 9);
  const int g = rem / 9;
  const int j = rem % 9;

  float tot[36];
#pragma unroll
  for (int i = 0; i < 36; ++i) tot[i] = 0.0f;
  for (int s = 0; s < SPLIT; ++s)
#pragma unroll
    for (int i = 0; i < 36; ++i) tot[i] += g_part[(tri * SPLIT + s) * 36 + i];

  float sq[8], gm[8][8];
#pragma unroll
  for (int i = 0; i < 8; ++i) sq[i] = tot[i];
  {
    int p = 8;
    for (int c = 0; c < 8; ++c)
      for (int d = c + 1; d < 8; ++d) {
        gm[c][d] = tot[p];
        gm[d][c] = tot[p];
        ++p;
      }
  }
  // per-row argmin with inf diagonal, first-occurrence tie-break
  int nn[8];
  for (int c = 0; c < 8; ++c) {
    float best = INFINITY;
    int bi = 0;
    for (int d = 0; d < 8; ++d) {
      if (d == c) continue;
      const float d2 = sq[c] + sq[d] - 2.0f * gm[c][d];
      if (d2 < best) {
        best = d2;
        bi = d;
      }
    }
    nn[c] = bi;
  }
  int um = 0;
  for (int c = 0; c < 8; ++c) um = um > nn[c] ? um : nn[c];
  int cnt = 0;
  for (int c = 0; c < 8; ++c) cnt += (nn[c] == um) ? 1 : 0;

  // scale = c_max/8 (exact: int * power of two); rel = neighbor offset
  // relative to the query pixel, constant over (h,w).
  const float sc = (float)cnt * 0.125f;
  const int fn = j * 8 + um;
  const int cn = fn / 9;
  const int kn = fn % 9;
  const int kin = kn / 3, kjn = kn % 3;
  for (int d = 0; d < 8; ++d) {
    const int f = j * 8 + d;
    const int cl = f / 9;
    const int k = f % 9;
    const int ki = k / 3, kj = k % 3;
    const int rel = (cn - cl) * HWSZ + (kin - ki) * WW + (kjn - kj);
    const int tix = (b * GG + g) * 72 + f;
    g_rel[tix] = rel;
    g_scl[tix] = sc;
  }
}

// -------- Phase 2: chunky blocks, table prologue, fused edge path --------
// v3: 1024 blocks (quarter-plane = 48 rows each), 9 float4-groups per
// thread. R2 post-mortem: per-block prologue must be amortized -- here it
// is 18 L2 loads (no barriers, no argmin) against ~2800 cyc of main work
// (~12% overhead, was ~300%). XCD swizzle keeps each (b,g) unit's 32
// blocks on one XCD. Edge groups (~4%) take the clamped scalar path.
__global__ __launch_bounds__(256) void phase2_kernel(
    const float* __restrict__ feat, float* __restrict__ out) {
  const int B = blockIdx.x;      // 0..1023
  const int xcd = B & 7;         // XCD-locality swizzle
  const int slot = B >> 3;       // 0..127
  const int unit = xcd * 4 + slot / 32; // (b,g) composite, 0..31
  const int r = slot % 32;
  const int cl = r / 4;          // local channel 0..7
  const int qblk = r % 4;        // quarter-plane index
  const int plane = unit * 8 + cl; // == b*CC + ch
  const int tid = (int)threadIdx.x;

  const int tbase = unit * 72 + cl * 9;
  int rel[9];
  float scl[9];
#pragma unroll
  for (int k = 0; k < 9; ++k) {
    rel[k] = g_rel[tbase + k];
    scl[k] = g_scl[tbase + k];
  }

  const float* pb = feat + (size_t)plane * HWSZ;
  float* ob = out + (size_t)plane * HWSZ;
  const bool b1 = (unit >= GG); // b != 0
  const int i0 = qblk * 9216 + tid * 4; // 9216 px = 48 rows per block

  for (int gidx = 0; gidx < 9; ++gidx) {
    const int inner = i0 + gidx * 1024;
    const int h = inner / WW;
    const int w0 = inner % WW; // always a multiple of 4 (WW % 4 == 0)
    if (h >= 2 && h < HM && w0 >= 4 && w0 < 188) {
      // interior: all 9 neighbors valid for all 4 px
      const float* p = pb + inner;
      const float4v v = *(const float4v*)p;
      float4v acc = {0.0f, 0.0f, 0.0f, 0.0f};
#pragma unroll
      for (int k = 0; k < 9; ++k) {
        const float4a n = *(const float4a*)(p + rel[k]);
        const float s = scl[k];
        // exact reference op order: floor(v*n*cm/8) == floor(v*n*(cm/8))
        acc.x += floorf(v.x * n.x * s);
        acc.y += floorf(v.y * n.y * s);
        acc.z += floorf(v.z * n.z * s);
        acc.w += floorf(v.w * n.w * s);
      }
      if (b1) { // interior => n_valid = 9
        acc.x += 9.0f * v.x;
        acc.y += 9.0f * v.y;
        acc.z += 9.0f * v.z;
        acc.w += 9.0f * v.w;
      }
      *(float4v*)(ob + inner) = acc;
    } else {
      // border: clamped scalar path (exec-masked for interior lanes)
#pragma unroll
      for (int e = 0; e < 4; ++e) {
        const int w = w0 + e;
        const float* p = pb + inner + e;
        const float v = *p;
        float acc = 0.0f;
        int nv = 0;
#pragma unroll
        for (int k = 0; k < 9; ++k) {
          const int ki = k / 3, kj = k % 3; // compile-time
          const int y = h - ki, x = w - kj;
          const bool valid =
              ((unsigned)y < (unsigned)HM) & ((unsigned)x < (unsigned)WM);
          const int o = valid ? rel[k] : 0; // clamp keeps the load in-bounds
          const float n = p[o];
          const float fl = floorf(v * n * scl[k]);
          acc += valid ? fl : 0.0f;
          nv += valid ? 1 : 0;
        }
        if (b1) acc += (float)nv * v;
        ob[inner + e] = acc;
      }
    }
  }
}

extern "C" void kernel_launch(void* const* d_in, const int* in_sizes, int n_in,
                              void* d_out, int out_size, void* d_ws,
                              size_t ws_size, hipStream_t stream) {
  const float* feat = (const float*)d_in[0];
  float* out = (float*)d_out;
  (void)d_ws;
  (void)ws_size;
  (void)in_sizes;
  (void)n_in;
  (void)out_size;

  phase1_kernel<<<NTRIPLE * SPLIT, 256, 0, stream>>>(feat);
  phase1b_kernel<<<(NTRIPLE + 63) / 64, 64, 0, stream>>>();
  phase2_kernel<<<BB * CC * 4, 256, 0, stream>>>(feat, out);
}